// Round 12
// baseline (986.487 us; speedup 1.0000x reference)
//
#include <hip/hip_runtime.h>
#include <math.h>

#define D_FEAT 64
#define SCAN_BLOCK 1024
#define NG 8            // edge groups (one per XCD; private counters + sub-buckets)
#define NR 8            // dst ranges (XCD-local scatter/placement)
#define C2 32768        // capacity per (g,r) sub-bucket (mean ~19.5K for 1.25M edges)

// ---------------------------------------------------------------------------
// main ws layout (ints):
//   ctrl       : 80    (bcnt[g*8+r] 64 | ocnt @64 | pad)   -- memset-zeroed
//   priv       : NG*n  (counts -> relative prefixes -> cursors) -- memset-zeroed
//   offsets    : n+1   (TILE-LOCAL exclusive prefixes)
//   blocksums  : 128   (raw per-tile totals)
//   bsrc,bdst  : 64*C2 each  (sub-buckets [g][r])
//   osrc,odg   : n_edges each (overflow, g packed in bits 20..22 of odg)
//   sorted_src : n_edges
// fallback ws (R10): counts n | cursor n | offsets n+1 | blocksums 128 | E
// ---------------------------------------------------------------------------

// wave-shuffle block exclusive scan; requires blockDim.x == 1024
__device__ __forceinline__ int block_scan_excl_1024(int v, int* smem16) {
    int lane = threadIdx.x & 63;
    int wid  = threadIdx.x >> 6;
    int x = v;
    #pragma unroll
    for (int d = 1; d < 64; d <<= 1) {
        int t = __shfl_up(x, d, 64);
        if (lane >= d) x += t;
    }
    if (lane == 63) smem16[wid] = x;
    __syncthreads();
    if (wid == 0) {
        int s = (lane < 16) ? smem16[lane] : 0;
        #pragma unroll
        for (int d = 1; d < 16; d <<= 1) {
            int t = __shfl_up(s, d, 64);
            if (lane >= d) s += t;
        }
        if (lane < 16) smem16[lane] = s;
    }
    __syncthreads();
    int base = (wid > 0) ? smem16[wid - 1] : 0;
    return base + x - v;
}

// 0..128 exclusive-prefix table of blocksums into LDS (one wave does the work).
__device__ __forceinline__ void build_pfx_lds(const int* __restrict__ blocksums,
                                              int ntiles, int* pfx) {
    int tid = threadIdx.x;
    if (tid < 64) {
        int a = (tid < ntiles) ? blocksums[tid] : 0;
        int b = (tid + 64 < ntiles) ? blocksums[tid + 64] : 0;
        int A = a;
        #pragma unroll
        for (int d = 1; d < 64; d <<= 1) {
            int t = __shfl_up(A, d, 64);
            if (tid >= d) A += t;
        }
        int totalA = __shfl(A, 63, 64);
        int B = b;
        #pragma unroll
        for (int d = 1; d < 64; d <<= 1) {
            int t = __shfl_up(B, d, 64);
            if (tid >= d) B += t;
        }
        B += totalA;
        if (tid == 0) pfx[0] = 0;
        pfx[tid + 1] = A;
        pfx[tid + 65] = B;
    }
    __syncthreads();
}

// ================= Pass A: fused bin + count (edge list read ONCE) =========

__global__ void bin_count_kernel(const int* __restrict__ src,
                                 const int* __restrict__ dst,
                                 int* __restrict__ priv,
                                 int* __restrict__ bsrc, int* __restrict__ bdst,
                                 int* __restrict__ osrc, int* __restrict__ odg,
                                 int* __restrict__ ctrl,
                                 int n_nodes, int n_edges, int egroup, int npr) {
    int g = blockIdx.x & (NG - 1);
    int c = blockIdx.x >> 3;
    int nchunks = gridDim.x >> 3;
    int ebeg = g * egroup;
    int eend = ebeg + egroup; if (eend > n_edges) eend = n_edges;
    int lane = threadIdx.x & 63;
    int* cnt = priv + (size_t)g * n_nodes;
    int* myctrl = ctrl + g * NR;          // 8 XCD-local cursors for this group
    int stride = nchunks * blockDim.x;

    for (int e0 = ebeg + c * blockDim.x; e0 < eend; e0 += stride) {
        int e = e0 + threadIdx.x;
        bool act = (e < eend);
        int s = 0, d = 0, r = 0;
        if (act) {
            s = src[e];
            d = dst[e];
            atomicAdd(&cnt[d], 1);
            r = d / npr; if (r > NR - 1) r = NR - 1;
        }
        // ballot-aggregated append: one cursor atomic per (wave, range)
        #pragma unroll
        for (int rr = 0; rr < NR; ++rr) {
            unsigned long long mask = __ballot(act && (r == rr));
            if (mask == 0ULL) continue;
            int leader = __ffsll(mask) - 1;
            int num = __popcll(mask);
            int base = 0;
            if (lane == leader) base = atomicAdd(&myctrl[rr], num);
            base = __shfl(base, leader, 64);
            if (act && r == rr) {
                int rank = __popcll(mask & ((1ULL << lane) - 1ULL));
                int pos = base + rank;
                if (pos < C2) {
                    size_t off = ((size_t)(g * NR + rr)) * C2 + pos;
                    bsrc[off] = s;
                    bdst[off] = d;
                } else {                          // overflow (empty for uniform dst)
                    int op = atomicAdd(&ctrl[64], 1);
                    if (op < n_edges) { osrc[op] = s; odg[op] = d | (g << 20); }
                }
            }
        }
    }
}

// ================= scan phase (one dispatch, R10 scheme) ===================

__global__ void scanA_fused_kernel(int* __restrict__ priv,
                                   int* __restrict__ offsets,
                                   int* __restrict__ blocksums, int n_nodes) {
    __shared__ int smem16[16];
    int i = blockIdx.x * SCAN_BLOCK + threadIdx.x;
    int total = 0;
    if (i < n_nodes) {
        int run = 0;
        #pragma unroll
        for (int g = 0; g < NG; ++g) {
            size_t idx = (size_t)g * n_nodes + i;
            int t = priv[idx];
            priv[idx] = run;
            run += t;
        }
        total = run;
    }
    int excl = block_scan_excl_1024(total, smem16);
    if (i < n_nodes) offsets[i] = excl;                 // tile-local
    if (threadIdx.x == SCAN_BLOCK - 1) blocksums[blockIdx.x] = excl + total;
}

// ================= Pass C: scatter from buckets (all lanes useful) =========

__global__ void scatter_buckets_kernel(const int* __restrict__ bsrc,
                                       const int* __restrict__ bdst,
                                       const int* __restrict__ osrc,
                                       const int* __restrict__ odg,
                                       const int* __restrict__ ctrl,
                                       const int* __restrict__ offsets,
                                       const int* __restrict__ blocksums,
                                       int* __restrict__ priv,
                                       int* __restrict__ sorted_src,
                                       int n_nodes, int n_edges, int ntiles) {
    __shared__ int pfx[130];
    build_pfx_lds(blocksums, ntiles, pfx);

    int r = blockIdx.x & (NR - 1);
    int c = blockIdx.x >> 3;
    int nchunks = gridDim.x >> 3;
    int stride = nchunks * blockDim.x;

    // 8 sub-buckets feed range r; cursor atomics + sorted writes are XCD-r local
    for (int g = 0; g < NG; ++g) {
        int cnt = ctrl[g * NR + r]; if (cnt > C2) cnt = C2;
        const int* bs = bsrc + ((size_t)(g * NR + r)) * C2;
        const int* bd = bdst + ((size_t)(g * NR + r)) * C2;
        int* cur = priv + (size_t)g * n_nodes;
        for (int i = c * blockDim.x + threadIdx.x; i < cnt; i += stride) {
            int s = bs[i];
            int d = bd[i];
            int pos = offsets[d] + pfx[d >> 10] + atomicAdd(&cur[d], 1);
            sorted_src[pos] = s;
        }
    }
    // overflow: grid-wide, unordered-locality (normally empty)
    int ocnt = ctrl[64]; if (ocnt > n_edges) ocnt = n_edges;
    int gstride = gridDim.x * blockDim.x;
    for (int i = blockIdx.x * blockDim.x + threadIdx.x; i < ocnt; i += gstride) {
        int s = osrc[i];
        int dg = odg[i];
        int d = dg & 0xFFFFF;
        int g = dg >> 20;
        int pos = offsets[d] + pfx[d >> 10] + atomicAdd(&priv[(size_t)g * n_nodes + d], 1);
        sorted_src[pos] = s;
    }
}

// ===================== fallback build (R10 fallback path) ==================

__global__ void hist_part_kernel(const int* __restrict__ dst,
                                 int* __restrict__ counts,
                                 int n_edges, int nodes_per_range) {
    int r = blockIdx.x & (NR - 1);
    int c = blockIdx.x / NR;
    int nchunks = gridDim.x / NR;
    int lo = r * nodes_per_range;
    int hi = lo + nodes_per_range;
    int stride = nchunks * blockDim.x;
    for (int e = c * blockDim.x + threadIdx.x; e < n_edges; e += stride) {
        int d = dst[e];
        if (d >= lo && d < hi) atomicAdd(&counts[d], 1);
    }
}

__global__ void scanA_plain_kernel(const int* __restrict__ counts,
                                   int* __restrict__ offsets,
                                   int* __restrict__ blocksums, int n) {
    __shared__ int smem16[16];
    int i = blockIdx.x * SCAN_BLOCK + threadIdx.x;
    int v = (i < n) ? counts[i] : 0;
    int e = block_scan_excl_1024(v, smem16);
    if (i < n) offsets[i] = e;
    if (threadIdx.x == SCAN_BLOCK - 1) blocksums[blockIdx.x] = e + v;
}

__global__ void scatter_fb_kernel(const int* __restrict__ src,
                                  const int* __restrict__ dst,
                                  const int* __restrict__ offsets,
                                  const int* __restrict__ blocksums,
                                  int* __restrict__ cursor,
                                  int* __restrict__ sorted_src,
                                  int n_edges, int nodes_per_range, int ntiles) {
    __shared__ int pfx[130];
    build_pfx_lds(blocksums, ntiles, pfx);
    int r = blockIdx.x & (NR - 1);
    int c = blockIdx.x / NR;
    int nchunks = gridDim.x / NR;
    int lo = r * nodes_per_range;
    int hi = lo + nodes_per_range;
    int stride = nchunks * blockDim.x;
    for (int e = c * blockDim.x + threadIdx.x; e < n_edges; e += stride) {
        int d = dst[e];
        if (d >= lo && d < hi) {
            int pos = offsets[d] + pfx[d >> 10] + atomicAdd(&cursor[d], 1);
            sorted_src[pos] = src[e];
        }
    }
}

// ============================== pull phase =================================

// one wave per node; 4 groups x 16 lanes, float4 gathers, 2-deep unroll.
__global__ void pull_max_kernel(const float* __restrict__ inp,
                                const int* __restrict__ offsets,
                                const int* __restrict__ blocksums,
                                const int* __restrict__ sorted_src,
                                float* __restrict__ out,
                                int n_nodes, int n_edges) {
    int gtid = blockIdx.x * blockDim.x + threadIdx.x;
    int node = gtid >> 6;
    if (node >= n_nodes) return;
    int lane = threadIdx.x & 63;
    int g = lane >> 4;
    int l = lane & 15;

    int t = node >> 10;
    int contrib = ((lane < t) ? blocksums[lane] : 0) +
                  ((lane + 64 < t) ? blocksums[lane + 64] : 0);
    #pragma unroll
    for (int d = 32; d > 0; d >>= 1) contrib += __shfl_xor(contrib, d, 64);
    int base = contrib;

    int beg = offsets[node] + base;
    int end;
    if (node + 1 == n_nodes) {
        end = n_edges;
    } else {
        int t2 = (node + 1) >> 10;
        int base2 = (t2 == t) ? base : base + blocksums[t];
        end = offsets[node + 1] + base2;
    }

    const float4* inp4 = reinterpret_cast<const float4*>(inp);
    float4 own = inp4[(size_t)node * 16 + l];

    float4 m;
    m.x = -INFINITY; m.y = -INFINITY; m.z = -INFINITY; m.w = -INFINITY;
    int j = beg + g;
    for (; j + 4 < end; j += 8) {
        int s0 = sorted_src[j];
        int s1 = sorted_src[j + 4];
        float4 v0 = inp4[(size_t)s0 * 16 + l];
        float4 v1 = inp4[(size_t)s1 * 16 + l];
        m.x = fmaxf(m.x, fmaxf(v0.x, v1.x));
        m.y = fmaxf(m.y, fmaxf(v0.y, v1.y));
        m.z = fmaxf(m.z, fmaxf(v0.z, v1.z));
        m.w = fmaxf(m.w, fmaxf(v0.w, v1.w));
    }
    if (j < end) {
        int s = sorted_src[j];
        float4 v = inp4[(size_t)s * 16 + l];
        m.x = fmaxf(m.x, v.x);
        m.y = fmaxf(m.y, v.y);
        m.z = fmaxf(m.z, v.z);
        m.w = fmaxf(m.w, v.w);
    }
    m.x = fmaxf(m.x, __shfl_xor(m.x, 16, 64));
    m.y = fmaxf(m.y, __shfl_xor(m.y, 16, 64));
    m.z = fmaxf(m.z, __shfl_xor(m.z, 16, 64));
    m.w = fmaxf(m.w, __shfl_xor(m.w, 16, 64));
    m.x = fmaxf(m.x, __shfl_xor(m.x, 32, 64));
    m.y = fmaxf(m.y, __shfl_xor(m.y, 32, 64));
    m.z = fmaxf(m.z, __shfl_xor(m.z, 32, 64));
    m.w = fmaxf(m.w, __shfl_xor(m.w, 32, 64));

    if (beg == end) m = own;

    float4* out4 = reinterpret_cast<float4*>(out);
    if (lane < 16) {
        out4[(size_t)node * 32 + l] = own;
    } else if (lane < 32) {
        out4[(size_t)node * 32 + 16 + l] = m;
    }
}

// ===========================================================================

extern "C" void kernel_launch(void* const* d_in, const int* in_sizes, int n_in,
                              void* d_out, int out_size, void* d_ws, size_t ws_size,
                              hipStream_t stream) {
    const float* inp = (const float*)d_in[0];
    const int* src = (const int*)d_in[1];
    const int* dst = (const int*)d_in[2];
    float* out = (float*)d_out;

    int n_nodes = in_sizes[0] / D_FEAT;
    int n_edges = in_sizes[1];

    int ntiles = (n_nodes + SCAN_BLOCK - 1) / SCAN_BLOCK;
    int npr = (n_nodes + NR - 1) / NR;
    int egroup = (n_edges + NG - 1) / NG;

    int* ws = (int*)d_ws;
    size_t need_main = (80 + (size_t)NG * n_nodes + (n_nodes + 1) + 128 +
                        2 * (size_t)64 * C2 + 2 * (size_t)n_edges +
                        (size_t)n_edges) * sizeof(int);

    if (ws_size >= need_main && ntiles <= 128 && n_nodes < (1 << 20)) {
        // ---------------- main path (5 dispatches) ----------------
        int* ctrl = ws;                                  // 80
        int* priv = ctrl + 80;                           // NG*n
        int* offsets = priv + (size_t)NG * n_nodes;      // n+1
        int* blocksums = offsets + n_nodes + 1;          // 128
        int* bsrc = blocksums + 128;                     // 64*C2
        int* bdst = bsrc + (size_t)64 * C2;              // 64*C2
        int* osrc = bdst + (size_t)64 * C2;              // E
        int* odg = osrc + n_edges;                       // E
        int* sorted_src = odg + n_edges;                 // E

        hipMemsetAsync(ws, 0, (80 + (size_t)NG * n_nodes) * sizeof(int), stream);
        bin_count_kernel<<<NG * 256, 256, 0, stream>>>(src, dst, priv,
                                                       bsrc, bdst, osrc, odg, ctrl,
                                                       n_nodes, n_edges, egroup, npr);
        scanA_fused_kernel<<<ntiles, SCAN_BLOCK, 0, stream>>>(priv, offsets,
                                                              blocksums, n_nodes);
        scatter_buckets_kernel<<<NR * 256, 256, 0, stream>>>(bsrc, bdst, osrc, odg,
                                                             ctrl, offsets, blocksums,
                                                             priv, sorted_src,
                                                             n_nodes, n_edges, ntiles);
        {
            int total = n_nodes * 64;
            pull_max_kernel<<<(total + 255) / 256, 256, 0, stream>>>(
                inp, offsets, blocksums, sorted_src, out, n_nodes, n_edges);
        }
    } else {
        // ---------------- fallback path (R10, 5 dispatches) ----------------
        int* counts = ws;                                // n
        int* cursor = ws + n_nodes;                      // n
        int* offsets = cursor + n_nodes;                 // n+1
        int* blocksums = offsets + n_nodes + 1;          // 128
        int* sorted_src = blocksums + 128;               // E

        hipMemsetAsync(counts, 0, 2 * (size_t)n_nodes * sizeof(int), stream);
        hist_part_kernel<<<NR * 256, 256, 0, stream>>>(dst, counts, n_edges, npr);
        scanA_plain_kernel<<<ntiles, SCAN_BLOCK, 0, stream>>>(counts, offsets,
                                                              blocksums, n_nodes);
        scatter_fb_kernel<<<NR * 256, 256, 0, stream>>>(src, dst, offsets,
                                                        blocksums, cursor,
                                                        sorted_src, n_edges,
                                                        npr, ntiles);
        {
            int total = n_nodes * 64;
            pull_max_kernel<<<(total + 255) / 256, 256, 0, stream>>>(
                inp, offsets, blocksums, sorted_src, out, n_nodes, n_edges);
        }
    }
}